// Round 16
// baseline (2986.949 us; speedup 1.0000x reference)
//
#include <hip/hip_runtime.h>
#include <cstdint>
#include <cmath>

#define DIM_H 1024
#define DIM_Z 128
#define NBATCH 128
#define NT 512
#define A_DT   0.1f
#define OMA_DT 0.9f

typedef short bf16x8 __attribute__((ext_vector_type(8)));
typedef float f32x4  __attribute__((ext_vector_type(4)));
#define MFMA16 __builtin_amdgcn_mfma_f32_16x16x32_bf16

// ws layout (u32): [0]=identity flag; prog word per (g, rb, wave): [64 + g*128 + rb*4 + wv].
// byte 16384+: packed bf16 hx32[parity 2][128][1024] u32 = (lo16<<16)|hi16.
#define HX_BYTE_OFF 16384
#define HX_PAR_U32  131072

// ---- signal plane: SYSTEM scope (sc0 sc1) — proven liveness path ----
__device__ __forceinline__ void store_u32_dev(unsigned* p, unsigned v){
  asm volatile("global_store_dword %0, %1, off sc0 sc1" :: "v"(p), "v"(v) : "memory");
}
__device__ __forceinline__ unsigned load_u32_dev(const unsigned* p){
  unsigned r;
  asm volatile("global_load_dword %0, %1, off sc0 sc1\n\ts_waitcnt vmcnt(0)"
               : "=v"(r) : "v"(p) : "memory");
  return r;
}
// ---- data plane PROBE: DEVICE scope (sc1 only; CDNA SC[1:0]: 2=device).
// If insufficient, consumers read stale h -> absmax blows up (no hang:
// signals stay system-scope). Round-12 hang was sc0-only = SE scope.
__device__ __forceinline__ void store2_hx(unsigned* p, unsigned a, unsigned b){
  unsigned long long v = ((unsigned long long)b << 32) | a;
  asm volatile("global_store_dwordx2 %0, %1, off sc1" :: "v"(p), "v"(v) : "memory");
}
__device__ __forceinline__ uint4 load_u4_hx(const unsigned* p){
  uint4 r;
  asm volatile("global_load_dwordx4 %0, %1, off sc1" : "=v"(r) : "v"(p) : "memory");
  return r;
}
__device__ __forceinline__ void wait_vm0(){
  asm volatile("s_waitcnt vmcnt(0)" ::: "memory");
}
__device__ __forceinline__ unsigned cvt_pk_bf16(float a, float b){
  unsigned r;
  asm("v_cvt_pk_bf16_f32 %0, %1, %2" : "=v"(r) : "v"(a), "v"(b));
  return r;
}
// h -> packed (bf16(resid)<<16) | bf16(h)
__device__ __forceinline__ unsigned pack_hl(float h){
  unsigned t = cvt_pk_bf16(h, h);
  float res = h - __uint_as_float(t << 16);
  return cvt_pk_bf16(h, res);
}

__global__ void k_init(unsigned* w){
  int i = blockIdx.x*1024 + threadIdx.x;
  store_u32_dev(w + i, (i == 0) ? 1u : 0u);
}

__global__ void k_check(const float* __restrict__ Bs, const float* __restrict__ Bu,
                        const float* __restrict__ bias, unsigned* w){
  const size_t n1 = (size_t)DIM_H * DIM_H;
  const size_t total = 2*n1 + DIM_H;
  bool bad = false;
  for (size_t e = (size_t)blockIdx.x*blockDim.x + threadIdx.x; e < total;
       e += (size_t)gridDim.x*blockDim.x){
    float v, ex;
    if (e < n1)       { v = Bs[e];      ex = ((e>>10)==(e&1023)) ? 1.f : 0.f; }
    else if (e < 2*n1){ size_t e2=e-n1; v = Bu[e2]; ex = ((e2>>10)==(e2&1023)) ? 1.f : 0.f; }
    else              { v = bias[e-2*n1]; ex = 0.f; }
    if (v != ex) bad = true;
  }
  if (bad) atomicAnd(&w[0], 0u);
}

// General (non-identity) drive path: drive(b,t) -> h_seq[b][t+1][:]. Early-exits
// for the actual inputs (flag==1).
__global__ void k_drive_general(const float* __restrict__ s_seq, const float* __restrict__ u_seq,
                                const float* __restrict__ Bs, const float* __restrict__ Bu,
                                const float* __restrict__ bias, float* __restrict__ hseq,
                                const unsigned* __restrict__ w){
  if (w[0]) return;
  __shared__ float sl[DIM_H], ul[DIM_H];
  for (int pt = blockIdx.x; pt < NBATCH*(NT-1); pt += gridDim.x){
    int b = pt/(NT-1), t = pt%(NT-1);
    const float* sp = s_seq + ((size_t)b*NT + t)*DIM_H;
    const float* up = u_seq + ((size_t)b*NT + t)*DIM_H;
    __syncthreads();
    for (int k = threadIdx.x; k < DIM_H; k += blockDim.x){ sl[k]=sp[k]; ul[k]=up[k]; }
    __syncthreads();
    for (int r = threadIdx.x; r < DIM_H; r += blockDim.x){
      float acc = bias[r];
      const float* br = Bs + (size_t)r*DIM_H;
      const float* cr = Bu + (size_t)r*DIM_H;
      for (int k=0;k<DIM_H;k++) acc = fmaf(br[k], sl[k], acc);
      for (int k=0;k<DIM_H;k++) acc = fmaf(cr[k], ul[k], acc);
      hseq[((size_t)b*NT + (t+1))*DIM_H + r] = acc;
    }
  }
}

// MFMA recurrence: 256 blocks x 256 threads (4 waves), 1 block/CU.
// Group g = blockIdx>>5: batches [g*16,g*16+16); rb = blockIdx&31: rows
// [rb*32,rb*32+32). W bf16 hi/lo fragments in LDS. hx exchange = packed u32
// parity-dbuf planes (DEVICE scope probe); signals system-scope.
// Per-wave signals; wave kq polls its 8 K-quarter producer blocks x 4 waves.
// Adjacent-row epilogue: thread owns rows (2r, 2r+1) -> dwordx2 hx store,
// float2 hseq store, float2 s/u prefetch.
__attribute__((amdgpu_flat_work_group_size(256,256)))
__attribute__((amdgpu_waves_per_eu(1)))
__global__ void k_rnn(const float* __restrict__ h0, const float* __restrict__ s_seq,
                      const float* __restrict__ u_seq, const float* __restrict__ W,
                      const float* __restrict__ bias, float* __restrict__ hseq,
                      unsigned* __restrict__ wsp){
  const int tid  = threadIdx.x;
  const int lane = tid & 63;
  const int kq   = tid >> 6;          // wave = K-quarter 0..3
  const int g    = blockIdx.x >> 5;
  const int rb   = blockIdx.x & 31;
  const int row0 = rb * 32;
  const int b0   = g * 16;
  unsigned* prog = wsp + 64 + g*128;  // 32 blocks x 4 waves per group
  const int fast = (int)wsp[0];
  unsigned* hx32 = (unsigned*)((char*)wsp + HX_BYTE_OFF);

  __shared__ __align__(16) unsigned WL[2][2][32][256];  // W bf16 hi/lo frags, 128 KB
  __shared__ __align__(16) float LP[2][2][4][64][4];    // partials, t-parity dbuf, 16 KB

  // ---- one-time: W slice f32 -> bf16 hi/lo fragments in LDS ----
  {
    const int crl = tid >> 3;            // local row 0..31
    const int rt = crl >> 4, lr = crl & 15;
    const int kbase = (tid & 7) * 128;
    const float* wr = W + (size_t)(row0 + crl)*DIM_H + kbase;
    for (int kk = 0; kk < 128; kk += 8){
      int k = kbase + kk;
      float4 x = *(const float4*)(wr + kk);
      float4 y = *(const float4*)(wr + kk + 4);
      unsigned h01 = cvt_pk_bf16(x.x, x.y), h23 = cvt_pk_bf16(x.z, x.w);
      unsigned h45 = cvt_pk_bf16(y.x, y.y), h67 = cvt_pk_bf16(y.z, y.w);
      float l0 = x.x - __uint_as_float(h01 << 16);
      float l1 = x.y - __uint_as_float(h01 & 0xffff0000u);
      float l2 = x.z - __uint_as_float(h23 << 16);
      float l3 = x.w - __uint_as_float(h23 & 0xffff0000u);
      float l4 = y.x - __uint_as_float(h45 << 16);
      float l5 = y.y - __uint_as_float(h45 & 0xffff0000u);
      float l6 = y.z - __uint_as_float(h67 << 16);
      float l7 = y.w - __uint_as_float(h67 & 0xffff0000u);
      unsigned L01 = cvt_pk_bf16(l0, l1), L23 = cvt_pk_bf16(l2, l3);
      unsigned L45 = cvt_pk_bf16(l4, l5), L67 = cvt_pk_bf16(l6, l7);
      int c = k >> 5, kg = (k & 31) >> 3, li = kg*16 + lr;
      *(uint4*)&WL[rt][0][c][li*4] = make_uint4(h01, h23, h45, h67);
      *(uint4*)&WL[rt][1][c][li*4] = make_uint4(L01, L23, L45, L67);
    }
  }

  // ---- epilogue ownership: thread -> batch bl, adjacent local rows (2r, 2r+1) ----
  const int rwp = tid & 15;            // row-pair index 0..15
  const int bl  = tid >> 4;            // batch 0..15 (wave wv owns 4wv..4wv+3)
  const int bb  = b0 + bl;
  const int R0  = 2*rwp;               // local row, even
  const int tle = rwp >> 3;            // row-tile 0/1
  const int r0in = R0 & 15;            // row within tile (even)
  const int laneC = ((r0in >> 2) << 4) | bl;
  const int regC  = r0in & 3;          // 0 or 2; pair uses regC, regC+1
  const int rg0 = row0 + R0;           // global rows rg0, rg0+1
  const float bias0 = bias[rg0], bias1 = bias[rg0 + 1];

  // B-frag base (u32 elems): batch (b0 + lane&15), k = kq*256 + (lane>>4)*8
  const size_t loffu = (size_t)(b0 + (lane & 15))*1024 + kq*256 + (lane >> 4)*8;
  const unsigned* pB0 = hx32 + loffu;
  const unsigned* pB1 = hx32 + HX_PAR_U32 + loffu;

  // ---- init: h0 -> regs + hseq + hx parity0 ----
  float hold0 = h0[(size_t)bb*DIM_H + rg0];
  float hold1 = h0[(size_t)bb*DIM_H + rg0 + 1];
  *(float2*)&hseq[((size_t)bb*NT + 0)*DIM_H + rg0] = make_float2(hold0, hold1);
  store2_hx(hx32 + (size_t)bb*1024 + rg0, pack_hl(hold0), pack_hl(hold1));
  float sv0=0.f, uv0=0.f, sv1=0.f, uv1=0.f;
  if (fast){
    size_t o = ((size_t)bb*NT + 0)*DIM_H + rg0;
    float2 s2 = *(const float2*)(s_seq + o);
    float2 u2 = *(const float2*)(u_seq + o);
    sv0 = s2.x; sv1 = s2.y; uv0 = u2.x; uv1 = u2.y;
  }
  wait_vm0();                          // per-wave: own h0 hx stores drained
  __syncthreads();                     // WL fragments complete before any MFMA
  if (lane == 0) store_u32_dev(prog + rb*4 + kq, 1u);

  for (int t = 0; t < NT-1; t++){
    // ---- drive for THIS step; issue NEXT s/u prefetch (drains in poll shadow) ----
    float dv0, dv1;
    if (fast){
      dv0 = sv0 + uv0 + bias0;
      dv1 = sv1 + uv1 + bias1;
      size_t o = ((size_t)bb*NT + (t+1))*DIM_H + rg0;
      float2 s2 = *(const float2*)(s_seq + o);
      float2 u2 = *(const float2*)(u_seq + o);
      sv0 = s2.x; sv1 = s2.y; uv0 = u2.x; uv1 = u2.y;
    } else {
      float2 d2 = *(const float2*)(hseq + ((size_t)bb*NT + (t+1))*DIM_H + rg0);
      dv0 = d2.x; dv1 = d2.y;
    }

    // ---- per-wave poll: 8 producer blocks x 4 waves of this K-quarter ----
    {
      const unsigned tgt = (unsigned)(t+1);
      const unsigned* pp = prog + kq*32 + lane;   // rb'=kq*8+(lane>>2), wv'=lane&3
      unsigned v = tgt;
      for(;;){
        if (lane < 32) v = load_u32_dev(pp);
        if (__all(v >= tgt)) break;
        __builtin_amdgcn_s_sleep(1);
      }
    }

    // ---- B-fragment loads (packed u32, device scope) ----
    const unsigned* pB = (t & 1) ? pB1 : pB0;
    uint4 sB[8][2];
    #pragma unroll
    for (int ks = 0; ks < 8; ks++){
      sB[ks][0] = load_u4_hx(pB + ks*32);
      sB[ks][1] = load_u4_hx(pB + ks*32 + 4);
    }

    wait_vm0();
    __builtin_amdgcn_sched_barrier(0);

    // ---- MFMA: 2 row-tiles x 4 split products over this wave's K-quarter ----
    f32x4 c00{0,0,0,0}, c01{0,0,0,0}, c02{0,0,0,0}, c03{0,0,0,0};
    f32x4 c10{0,0,0,0}, c11{0,0,0,0}, c12{0,0,0,0}, c13{0,0,0,0};
    #pragma unroll
    for (int ks = 0; ks < 8; ks++){
      uint4 wa = sB[ks][0], wb = sB[ks][1];
      uint4 bhu, blu;
      bhu.x = __builtin_amdgcn_perm(wa.y, wa.x, 0x05040100u);
      bhu.y = __builtin_amdgcn_perm(wa.w, wa.z, 0x05040100u);
      bhu.z = __builtin_amdgcn_perm(wb.y, wb.x, 0x05040100u);
      bhu.w = __builtin_amdgcn_perm(wb.w, wb.z, 0x05040100u);
      blu.x = __builtin_amdgcn_perm(wa.y, wa.x, 0x07060302u);
      blu.y = __builtin_amdgcn_perm(wa.w, wa.z, 0x07060302u);
      blu.z = __builtin_amdgcn_perm(wb.y, wb.x, 0x07060302u);
      blu.w = __builtin_amdgcn_perm(wb.w, wb.z, 0x07060302u);
      bf16x8 bh  = __builtin_bit_cast(bf16x8, bhu);
      bf16x8 bl2 = __builtin_bit_cast(bf16x8, blu);
      const int c = kq*8 + ks;
      bf16x8 a0h = *(const bf16x8*)&WL[0][0][c][lane*4];
      bf16x8 a0l = *(const bf16x8*)&WL[0][1][c][lane*4];
      bf16x8 a1h = *(const bf16x8*)&WL[1][0][c][lane*4];
      bf16x8 a1l = *(const bf16x8*)&WL[1][1][c][lane*4];
      c00 = MFMA16(a0h, bh,  c00, 0,0,0);
      c01 = MFMA16(a0h, bl2, c01, 0,0,0);
      c02 = MFMA16(a0l, bh,  c02, 0,0,0);
      c03 = MFMA16(a0l, bl2, c03, 0,0,0);
      c10 = MFMA16(a1h, bh,  c10, 0,0,0);
      c11 = MFMA16(a1h, bl2, c11, 0,0,0);
      c12 = MFMA16(a1l, bh,  c12, 0,0,0);
      c13 = MFMA16(a1l, bl2, c13, 0,0,0);
    }
    f32x4 C0 = (c00 + c01) + (c02 + c03);
    f32x4 C1 = (c10 + c11) + (c12 + c13);
    const int lpp = t & 1;
    *(f32x4*)&LP[lpp][0][kq][lane][0] = C0;
    *(f32x4*)&LP[lpp][1][kq][lane][0] = C1;
    __syncthreads();   // the ONLY block barrier per step: LP[lpp] ready; also gates
                       // epilogue writes behind ALL waves' polls (parity safety)

    // ---- epilogue: sum K-quarters, leak + tanh, fused hx store, per-wave signal ----
    float pre0 = (LP[lpp][tle][0][laneC][regC]   + LP[lpp][tle][1][laneC][regC])
               + (LP[lpp][tle][2][laneC][regC]   + LP[lpp][tle][3][laneC][regC]);
    float pre1 = (LP[lpp][tle][0][laneC][regC+1] + LP[lpp][tle][1][laneC][regC+1])
               + (LP[lpp][tle][2][laneC][regC+1] + LP[lpp][tle][3][laneC][regC+1]);
    float hn0 = OMA_DT*hold0 + A_DT*tanhf(pre0 + dv0);
    float hn1 = OMA_DT*hold1 + A_DT*tanhf(pre1 + dv1);
    hold0 = hn0; hold1 = hn1;
    {
      unsigned* hq = hx32 + (((t+1) & 1) ? HX_PAR_U32 : 0) + (size_t)bb*1024 + rg0;
      store2_hx(hq, pack_hl(hn0), pack_hl(hn1));
    }
    wait_vm0();                                    // per-wave drain of own hx store
    if (lane == 0) store_u32_dev(prog + rb*4 + kq, (unsigned)(t+2));
    // f32 output write AFTER the signal — off the critical path (read by k_z only)
    *(float2*)&hseq[((size_t)bb*NT + (t+1))*DIM_H + rg0] = make_float2(hn0, hn1);
  }
}

// z = Wz . h + bz for all (b,t). 16 positions per block. (f32 VALU path)
#define GLD_LDS16(gp, lp) \
  __builtin_amdgcn_global_load_lds((const __attribute__((address_space(1))) void*)(gp), \
                                   (__attribute__((address_space(3))) void*)(lp), 16, 0, 0)
#define DOT4(hv, wv, a) do { \
  a = fmaf((hv).x, (wv).x, a); a = fmaf((hv).y, (wv).y, a); \
  a = fmaf((hv).z, (wv).z, a); a = fmaf((hv).w, (wv).w, a); } while(0)

__device__ __forceinline__ float wave_sum64(float x){
  x += __int_as_float(__builtin_amdgcn_update_dpp(0, __float_as_int(x), 0x111, 0xf, 0xf, true));
  x += __int_as_float(__builtin_amdgcn_update_dpp(0, __float_as_int(x), 0x112, 0xf, 0xf, true));
  x += __int_as_float(__builtin_amdgcn_update_dpp(0, __float_as_int(x), 0x114, 0xf, 0xf, true));
  x += __int_as_float(__builtin_amdgcn_update_dpp(0, __float_as_int(x), 0x118, 0xf, 0xf, true));
  x += __int_as_float(__builtin_amdgcn_update_dpp(0, __float_as_int(x), 0x142, 0xf, 0xf, true));
  x += __int_as_float(__builtin_amdgcn_update_dpp(0, __float_as_int(x), 0x143, 0xf, 0xf, true));
  return x;
}

__launch_bounds__(256, 1)
__global__ void k_z(const float* __restrict__ hseq, const float* __restrict__ Wz,
                    const float* __restrict__ bz, float* __restrict__ z){
  const int tid = threadIdx.x, lane = tid & 63, wv = tid >> 6;
  const size_t pos0 = (size_t)blockIdx.x * 16;
  __shared__ __align__(16) float h_lds[16*DIM_H];
  __shared__ __align__(16) float out_lds[512];
  #pragma unroll
  for (int i=0;i<16;i++){
    const float* src = hseq + (pos0+i)*DIM_H + tid*4;
    GLD_LDS16(src, &h_lds[i*DIM_H + tid*4]);
  }
  asm volatile("s_waitcnt vmcnt(0)" ::: "memory");
  __syncthreads();
  const int ei = tid>>5, er = tid&31;
  for (int zg=0; zg<4; zg++){
    const int zr0 = zg*32;
    float4 wreg[8][4];
    const float* wr = Wz + (size_t)(zr0 + wv*8)*DIM_H + lane*4;
    #pragma unroll
    for (int rr=0;rr<8;rr++)
      #pragma unroll
      for (int c=0;c<4;c++)
        wreg[rr][c] = *(const float4*)(wr + (size_t)rr*DIM_H + c*256);
    #pragma unroll 2
    for (int i=0;i<16;i++){
      const float4* hp = (const float4*)&h_lds[i*DIM_H];
      float4 hv0 = hp[lane], hv1 = hp[lane+64], hv2 = hp[lane+128], hv3 = hp[lane+192];
      float acc[8];
      #pragma unroll
      for (int rr=0;rr<8;rr++){
        float s = 0.f;
        DOT4(hv0, wreg[rr][0], s); DOT4(hv1, wreg[rr][1], s);
        DOT4(hv2, wreg[rr][2], s); DOT4(hv3, wreg[rr][3], s);
        acc[rr] = s;
      }
      #pragma unroll
      for (int rr=0;rr<8;rr++){
        float v = wave_sum64(acc[rr]);
        if (lane==63) out_lds[wv*128 + i*8 + rr] = v;
      }
    }
    __syncthreads();
    const int zr = zr0 + er;
    float v1 = out_lds[(er>>3)*128 + ei*8     + (er&7)] + bz[zr];
    float v2 = out_lds[(er>>3)*128 + (ei+8)*8 + (er&7)] + bz[zr];
    z[(pos0+ei)*DIM_Z + zr]   = v1;
    z[(pos0+ei+8)*DIM_Z + zr] = v2;
    __syncthreads();
  }
}

extern "C" void kernel_launch(void* const* d_in, const int* in_sizes, int n_in,
                              void* d_out, int out_size, void* d_ws, size_t ws_size,
                              hipStream_t stream){
  const float* h0    = (const float*)d_in[0];
  const float* s_seq = (const float*)d_in[1];
  const float* u_seq = (const float*)d_in[2];
  const float* W     = (const float*)d_in[3];
  const float* bias  = (const float*)d_in[4];
  const float* Bs    = (const float*)d_in[5];
  const float* Bu    = (const float*)d_in[6];
  const float* Wz    = (const float*)d_in[7];
  const float* bz    = (const float*)d_in[8];
  float* hseq = (float*)d_out;
  float* z    = hseq + (size_t)NBATCH*NT*DIM_H;
  unsigned* w = (unsigned*)d_ws;

  k_init<<<4, 1024, 0, stream>>>(w);
  k_check<<<256, 256, 0, stream>>>(Bs, Bu, bias, w);
  k_drive_general<<<2048, 256, 0, stream>>>(s_seq, u_seq, Bs, Bu, bias, hseq, w);
  {
    void* args[] = {(void*)&h0, (void*)&s_seq, (void*)&u_seq, (void*)&W,
                    (void*)&bias, (void*)&hseq, (void*)&w};
    hipError_t rc = hipLaunchCooperativeKernel((const void*)k_rnn, dim3(256), dim3(256),
                                               args, 0, stream);
    if (rc != hipSuccess){
      // 256 blocks == CU count, 1 block/CU by LDS budget: co-resident regardless.
      k_rnn<<<256, 256, 0, stream>>>(h0, s_seq, u_seq, W, bias, hseq, w);
    }
  }
  k_z<<<(NBATCH*NT)/16, 256, 0, stream>>>(hseq, Wz, bz, z);
}

// Round 18
// 2749.703 us; speedup vs baseline: 1.0863x; 1.0863x over previous
//
#include <hip/hip_runtime.h>
#include <cstdint>
#include <cmath>

#define DIM_H 1024
#define DIM_Z 128
#define NBATCH 128
#define NT 512
#define A_DT   0.1f
#define OMA_DT 0.9f

typedef short bf16x8 __attribute__((ext_vector_type(8)));
typedef float f32x4  __attribute__((ext_vector_type(4)));
#define MFMA16 __builtin_amdgcn_mfma_f32_16x16x32_bf16

// ws layout (u32): [0]=identity flag; prog[g][rb] at [64 + g*64 + rb] (g<8, rb<32).
// byte 16384+: packed bf16 hx32[parity 2][128][1024] u32 = (lo16<<16)|hi16 (1 MB).
// byte 1310720+: Wz bf16 hi/lo fragment planes [zt 8][pl 2][c 32][256] u32 (512 KB).
#define HX_BYTE_OFF 16384
#define HX_PAR_U32  131072
#define WZ_BYTE_OFF 1310720

// ---- device-scope (MALL) memory ops: sc0 sc1 (proven path; sc0-only = SE scope, hangs) ----
__device__ __forceinline__ void store_u32_dev(unsigned* p, unsigned v){
  asm volatile("global_store_dword %0, %1, off sc0 sc1" :: "v"(p), "v"(v) : "memory");
}
__device__ __forceinline__ uint4 load_u4_dev(const unsigned* p){
  uint4 r;
  asm volatile("global_load_dwordx4 %0, %1, off sc0 sc1" : "=v"(r) : "v"(p) : "memory");
  return r;
}
__device__ __forceinline__ unsigned load_u32_dev(const unsigned* p){
  unsigned r;
  asm volatile("global_load_dword %0, %1, off sc0 sc1\n\ts_waitcnt vmcnt(0)"
               : "=v"(r) : "v"(p) : "memory");
  return r;
}
__device__ __forceinline__ void wait_vm0(){
  asm volatile("s_waitcnt vmcnt(0)" ::: "memory");
}
__device__ __forceinline__ unsigned cvt_pk_bf16(float a, float b){
  unsigned r;
  asm("v_cvt_pk_bf16_f32 %0, %1, %2" : "=v"(r) : "v"(a), "v"(b));
  return r;
}
// h -> packed (bf16(resid)<<16) | bf16(h)
__device__ __forceinline__ unsigned pack_hl(float h){
  unsigned t = cvt_pk_bf16(h, h);
  float res = h - __uint_as_float(t << 16);
  return cvt_pk_bf16(h, res);
}

// split 8 f32 -> hi/lo bf16 frag words (function, not macro: avoids the
// macro-parameter / .x .y field-name token collision that broke round 17)
__device__ __forceinline__ void split8(float4 a, float4 b, uint4& H, uint4& L){
  H.x = cvt_pk_bf16(a.x, a.y); H.y = cvt_pk_bf16(a.z, a.w);
  H.z = cvt_pk_bf16(b.x, b.y); H.w = cvt_pk_bf16(b.z, b.w);
  float l0 = a.x - __uint_as_float(H.x << 16);
  float l1 = a.y - __uint_as_float(H.x & 0xffff0000u);
  float l2 = a.z - __uint_as_float(H.y << 16);
  float l3 = a.w - __uint_as_float(H.y & 0xffff0000u);
  float l4 = b.x - __uint_as_float(H.z << 16);
  float l5 = b.y - __uint_as_float(H.z & 0xffff0000u);
  float l6 = b.z - __uint_as_float(H.w << 16);
  float l7 = b.w - __uint_as_float(H.w & 0xffff0000u);
  L.x = cvt_pk_bf16(l0, l1); L.y = cvt_pk_bf16(l2, l3);
  L.z = cvt_pk_bf16(l4, l5); L.w = cvt_pk_bf16(l6, l7);
}

__global__ void k_init(unsigned* w){
  int i = blockIdx.x*1024 + threadIdx.x;
  w[i] = (i == 0) ? 1u : 0u;
}

__global__ void k_check(const float* __restrict__ Bs, const float* __restrict__ Bu,
                        const float* __restrict__ bias, unsigned* w){
  const size_t n1 = (size_t)DIM_H * DIM_H;
  const size_t total = 2*n1 + DIM_H;
  bool bad = false;
  for (size_t e = (size_t)blockIdx.x*blockDim.x + threadIdx.x; e < total;
       e += (size_t)gridDim.x*blockDim.x){
    float v, ex;
    if (e < n1)       { v = Bs[e];      ex = ((e>>10)==(e&1023)) ? 1.f : 0.f; }
    else if (e < 2*n1){ size_t e2=e-n1; v = Bu[e2]; ex = ((e2>>10)==(e2&1023)) ? 1.f : 0.f; }
    else              { v = bias[e-2*n1]; ex = 0.f; }
    if (v != ex) bad = true;
  }
  if (bad) atomicAnd(&w[0], 0u);
}

// Wz f32 -> bf16 hi/lo fragment planes in d_ws (once; 4 blocks x 32 z-rows).
__global__ void k_wz(const float* __restrict__ Wz, unsigned* __restrict__ wz32){
  const int tid = threadIdx.x;
  const int crl = tid >> 3;
  const int grow = blockIdx.x*32 + crl;          // global z-row 0..127
  const int zt = grow >> 4, lr = grow & 15;
  const int kbase = (tid & 7) * 128;
  const float* wr = Wz + (size_t)grow*DIM_H + kbase;
  for (int kk = 0; kk < 128; kk += 8){
    int k = kbase + kk;
    float4 x = *(const float4*)(wr + kk);
    float4 y = *(const float4*)(wr + kk + 4);
    uint4 H, L;
    split8(x, y, H, L);
    int c = k >> 5, kg = (k & 31) >> 3, li = kg*16 + lr;
    *(uint4*)&wz32[(((size_t)zt*2 + 0)*32 + c)*256 + li*4] = H;
    *(uint4*)&wz32[(((size_t)zt*2 + 1)*32 + c)*256 + li*4] = L;
  }
}

// General (non-identity) drive path: drive(b,t) -> h_seq[b][t+1][:]. Early-exits
// for the actual inputs (flag==1).
__global__ void k_drive_general(const float* __restrict__ s_seq, const float* __restrict__ u_seq,
                                const float* __restrict__ Bs, const float* __restrict__ Bu,
                                const float* __restrict__ bias, float* __restrict__ hseq,
                                const unsigned* __restrict__ w){
  if (w[0]) return;
  __shared__ float sl[DIM_H], ul[DIM_H];
  for (int pt = blockIdx.x; pt < NBATCH*(NT-1); pt += gridDim.x){
    int b = pt/(NT-1), t = pt%(NT-1);
    const float* sp = s_seq + ((size_t)b*NT + t)*DIM_H;
    const float* up = u_seq + ((size_t)b*NT + t)*DIM_H;
    __syncthreads();
    for (int k = threadIdx.x; k < DIM_H; k += blockDim.x){ sl[k]=sp[k]; ul[k]=up[k]; }
    __syncthreads();
    for (int r = threadIdx.x; r < DIM_H; r += blockDim.x){
      float acc = bias[r];
      const float* br = Bs + (size_t)r*DIM_H;
      const float* cr = Bu + (size_t)r*DIM_H;
      for (int k=0;k<DIM_H;k++) acc = fmaf(br[k], sl[k], acc);
      for (int k=0;k<DIM_H;k++) acc = fmaf(cr[k], ul[k], acc);
      hseq[((size_t)b*NT + (t+1))*DIM_H + r] = acc;
    }
  }
}

// MFMA recurrence — ROUND-13 VERBATIM (best measured: 2517 us).
__attribute__((amdgpu_flat_work_group_size(256,256)))
__attribute__((amdgpu_waves_per_eu(1)))
__global__ void k_rnn(const float* __restrict__ h0, const float* __restrict__ s_seq,
                      const float* __restrict__ u_seq, const float* __restrict__ W,
                      const float* __restrict__ bias, float* __restrict__ hseq,
                      unsigned* __restrict__ wsp){
  const int tid  = threadIdx.x;
  const int lane = tid & 63;
  const int kq   = tid >> 6;          // wave = K-quarter 0..3
  const int g    = blockIdx.x >> 5;
  const int rb   = blockIdx.x & 31;
  const int row0 = rb * 32;
  const int b0   = g * 16;
  unsigned* prog = wsp + 64 + g*64;
  const int fast = (int)wsp[0];
  unsigned* hx32 = (unsigned*)((char*)wsp + HX_BYTE_OFF);

  __shared__ __align__(16) unsigned WL[2][2][32][256];  // W bf16 hi/lo frags, 128 KB
  __shared__ __align__(16) float LP[2][4][64][4];       // cross-wave partials

  // ---- one-time: W slice f32 -> bf16 hi/lo fragments in LDS ----
  {
    const int crl = tid >> 3;            // local row 0..31
    const int rt = crl >> 4, lr = crl & 15;
    const int kbase = (tid & 7) * 128;
    const float* wr = W + (size_t)(row0 + crl)*DIM_H + kbase;
    for (int kk = 0; kk < 128; kk += 8){
      int k = kbase + kk;
      float4 x = *(const float4*)(wr + kk);
      float4 y = *(const float4*)(wr + kk + 4);
      uint4 H, L;
      split8(x, y, H, L);
      int c = k >> 5, kg = (k & 31) >> 3, li = kg*16 + lr;
      *(uint4*)&WL[rt][0][c][li*4] = H;
      *(uint4*)&WL[rt][1][c][li*4] = L;
    }
  }

  // ---- epilogue ownership: 2 outputs per thread ----
  const int rowin = tid & 15;
  const int bl    = tid >> 4;
  const int bb    = b0 + bl;
  const int r0g   = row0 + rowin;
  const int r1g   = row0 + 16 + rowin;
  const int laneC = ((rowin >> 2) << 4) | bl;
  const int regC  = rowin & 3;
  const float bias0 = bias[r0g], bias1 = bias[r1g];

  // B-frag base (u32 elems): batch (b0 + lane&15), k = kq*256 + (lane>>4)*8
  const size_t loffu = (size_t)(b0 + (lane & 15))*1024 + kq*256 + (lane >> 4)*8;
  const unsigned* pB0 = hx32 + loffu;
  const unsigned* pB1 = hx32 + HX_PAR_U32 + loffu;

  // ---- init: h0 -> regs + hseq + hx parity0 ----
  float hold0 = h0[(size_t)bb*DIM_H + r0g];
  float hold1 = h0[(size_t)bb*DIM_H + r1g];
  hseq[((size_t)bb*NT + 0)*DIM_H + r0g] = hold0;
  hseq[((size_t)bb*NT + 0)*DIM_H + r1g] = hold1;
  store_u32_dev(hx32 + (size_t)bb*1024 + r0g, pack_hl(hold0));
  store_u32_dev(hx32 + (size_t)bb*1024 + r1g, pack_hl(hold1));
  float sv0=0.f, uv0=0.f, sv1=0.f, uv1=0.f;
  if (fast){
    size_t o0 = ((size_t)bb*NT + 0)*DIM_H + r0g;
    size_t o1 = ((size_t)bb*NT + 0)*DIM_H + r1g;
    sv0 = s_seq[o0]; uv0 = u_seq[o0];
    sv1 = s_seq[o1]; uv1 = u_seq[o1];
  }
  wait_vm0();
  __syncthreads();
  if (tid == 0) store_u32_dev(prog + rb, 1u);

  for (int t = 0; t < NT-1; t++){
    // ---- drive for THIS step; issue NEXT s/u prefetch (drains in poll shadow) ----
    float dv0, dv1;
    if (fast){
      dv0 = sv0 + uv0 + bias0;
      dv1 = sv1 + uv1 + bias1;
      size_t o0 = ((size_t)bb*NT + (t+1))*DIM_H + r0g;
      size_t o1 = ((size_t)bb*NT + (t+1))*DIM_H + r1g;
      sv0 = s_seq[o0]; uv0 = u_seq[o0];
      sv1 = s_seq[o1]; uv1 = u_seq[o1];
    } else {
      dv0 = hseq[((size_t)bb*NT + (t+1))*DIM_H + r0g];
      dv1 = hseq[((size_t)bb*NT + (t+1))*DIM_H + r1g];
    }

    // ---- per-wave poll: only THIS K-quarter's 8 producer blocks ----
    {
      const unsigned tgt = (unsigned)(t+1);
      const unsigned* pp = prog + kq*8 + (lane & 7);
      unsigned v = tgt;
      for(;;){
        if (lane < 8) v = load_u32_dev(pp);
        if (__all(v >= tgt)) break;
        __builtin_amdgcn_s_sleep(1);
      }
    }

    // ---- B-fragment loads (packed u32, MALL) ----
    const unsigned* pB = (t & 1) ? pB1 : pB0;
    uint4 sB[8][2];
    #pragma unroll
    for (int ks = 0; ks < 8; ks++){
      sB[ks][0] = load_u4_dev(pB + ks*32);
      sB[ks][1] = load_u4_dev(pB + ks*32 + 4);
    }

    wait_vm0();
    __builtin_amdgcn_sched_barrier(0);

    // ---- MFMA: 2 row-tiles x 4 split products over this wave's K-quarter ----
    f32x4 c00{0,0,0,0}, c01{0,0,0,0}, c02{0,0,0,0}, c03{0,0,0,0};
    f32x4 c10{0,0,0,0}, c11{0,0,0,0}, c12{0,0,0,0}, c13{0,0,0,0};
    #pragma unroll
    for (int ks = 0; ks < 8; ks++){
      uint4 wa = sB[ks][0], wb = sB[ks][1];
      uint4 bhu, blu;
      bhu.x = __builtin_amdgcn_perm(wa.y, wa.x, 0x05040100u);
      bhu.y = __builtin_amdgcn_perm(wa.w, wa.z, 0x05040100u);
      bhu.z = __builtin_amdgcn_perm(wb.y, wb.x, 0x05040100u);
      bhu.w = __builtin_amdgcn_perm(wb.w, wb.z, 0x05040100u);
      blu.x = __builtin_amdgcn_perm(wa.y, wa.x, 0x07060302u);
      blu.y = __builtin_amdgcn_perm(wa.w, wa.z, 0x07060302u);
      blu.z = __builtin_amdgcn_perm(wb.y, wb.x, 0x07060302u);
      blu.w = __builtin_amdgcn_perm(wb.w, wb.z, 0x07060302u);
      bf16x8 bh  = __builtin_bit_cast(bf16x8, bhu);
      bf16x8 bl2 = __builtin_bit_cast(bf16x8, blu);
      const int c = kq*8 + ks;
      bf16x8 a0h = *(const bf16x8*)&WL[0][0][c][lane*4];
      bf16x8 a0l = *(const bf16x8*)&WL[0][1][c][lane*4];
      bf16x8 a1h = *(const bf16x8*)&WL[1][0][c][lane*4];
      bf16x8 a1l = *(const bf16x8*)&WL[1][1][c][lane*4];
      c00 = MFMA16(a0h, bh,  c00, 0,0,0);
      c01 = MFMA16(a0h, bl2, c01, 0,0,0);
      c02 = MFMA16(a0l, bh,  c02, 0,0,0);
      c03 = MFMA16(a0l, bl2, c03, 0,0,0);
      c10 = MFMA16(a1h, bh,  c10, 0,0,0);
      c11 = MFMA16(a1h, bl2, c11, 0,0,0);
      c12 = MFMA16(a1l, bh,  c12, 0,0,0);
      c13 = MFMA16(a1l, bl2, c13, 0,0,0);
    }
    f32x4 C0 = (c00 + c01) + (c02 + c03);
    f32x4 C1 = (c10 + c11) + (c12 + c13);
    *(f32x4*)&LP[0][kq][lane][0] = C0;
    *(f32x4*)&LP[1][kq][lane][0] = C1;
    __syncthreads();

    // ---- epilogue: sum K-quarters, leak + tanh, hx store, signal, hseq ----
    float pre0 = (LP[0][0][laneC][regC] + LP[0][1][laneC][regC])
               + (LP[0][2][laneC][regC] + LP[0][3][laneC][regC]);
    float pre1 = (LP[1][0][laneC][regC] + LP[1][1][laneC][regC])
               + (LP[1][2][laneC][regC] + LP[1][3][laneC][regC]);
    float hn0 = OMA_DT*hold0 + A_DT*tanhf(pre0 + dv0);
    float hn1 = OMA_DT*hold1 + A_DT*tanhf(pre1 + dv1);
    hold0 = hn0; hold1 = hn1;
    {
      unsigned* hq = hx32 + (((t+1) & 1) ? HX_PAR_U32 : 0) + (size_t)bb*1024;
      store_u32_dev(hq + r0g, pack_hl(hn0));
      store_u32_dev(hq + r1g, pack_hl(hn1));
    }
    wait_vm0();          // hx stores at MALL before signaling
    __syncthreads();     // all 256 threads' hx posted; also protects LP reuse
    if (tid == 0) store_u32_dev(prog + rb, (unsigned)(t+2));
    // f32 output write AFTER the signal — off the critical path (read by k_z only)
    hseq[((size_t)bb*NT + (t+1))*DIM_H + r0g] = hn0;
    hseq[((size_t)bb*NT + (t+1))*DIM_H + r1g] = hn1;
  }
}

// z = Wz . h + bz — MFMA bf16-split version. 16 positions per block; wave kq =
// K-quarter; A = Wz frags (precomputed planes, L2-resident), B = h (staged f32,
// padded LDS, converted per wave); chained-acc MFMA; LDS partial reduce.
#define HPAD 1028
__launch_bounds__(256, 1)
__global__ void k_z(const float* __restrict__ hseq, const unsigned* __restrict__ wz32,
                    const float* __restrict__ bz, float* __restrict__ z){
  const int tid = threadIdx.x, lane = tid & 63, kq = tid >> 6;
  const size_t pos0 = (size_t)blockIdx.x * 16;
  __shared__ __align__(16) float h_lds[16*HPAD];      // ~66 KB (padded: 2-way max)
  __shared__ __align__(16) float LPz[4][8][64][4];    // 32 KB

  // stage h: 16 positions x 1024 f32 (coalesced read, padded write)
  #pragma unroll
  for (int i = 0; i < 16; i++){
    float4 v = *(const float4*)(hseq + (pos0+i)*DIM_H + tid*4);
    *(float4*)&h_lds[i*HPAD + tid*4] = v;
  }
  __syncthreads();

  // B-frags for this wave: p = lane&15 (N=position), k = kq*256 + (lane>>4)*8 + ks*32
  const int p  = lane & 15;
  const int kb = kq*256 + (lane >> 4)*8;
  uint4 BH[8], BL[8];
  #pragma unroll
  for (int ks = 0; ks < 8; ks++){
    const float* hp = &h_lds[p*HPAD + kb + ks*32];
    float4 fa = *(const float4*)hp;
    float4 fb = *(const float4*)(hp + 4);
    split8(fa, fb, BH[ks], BL[ks]);
  }

  #pragma unroll
  for (int zt = 0; zt < 8; zt++){
    f32x4 acc{0,0,0,0};
    #pragma unroll
    for (int ks = 0; ks < 8; ks++){
      const int c = kq*8 + ks;
      uint4 ah4 = *(const uint4*)&wz32[(((size_t)zt*2 + 0)*32 + c)*256 + lane*4];
      uint4 al4 = *(const uint4*)&wz32[(((size_t)zt*2 + 1)*32 + c)*256 + lane*4];
      bf16x8 ah = __builtin_bit_cast(bf16x8, ah4);
      bf16x8 al = __builtin_bit_cast(bf16x8, al4);
      bf16x8 bh = __builtin_bit_cast(bf16x8, BH[ks]);
      bf16x8 bl = __builtin_bit_cast(bf16x8, BL[ks]);
      acc = MFMA16(ah, bh, acc, 0,0,0);
      acc = MFMA16(ah, bl, acc, 0,0,0);
      acc = MFMA16(al, bh, acc, 0,0,0);
      acc = MFMA16(al, bl, acc, 0,0,0);
    }
    *(f32x4*)&LPz[kq][zt][lane][0] = acc;
  }
  __syncthreads();

  // reduce K-quarters + bias + store. thread -> (position pc, row) per tile.
  const int pc = tid & 15, row = tid >> 4;
  const int laneC = ((row >> 2) << 4) | pc;
  const int regC  = row & 3;
  #pragma unroll
  for (int zt = 0; zt < 8; zt++){
    float pre = (LPz[0][zt][laneC][regC] + LPz[1][zt][laneC][regC])
              + (LPz[2][zt][laneC][regC] + LPz[3][zt][laneC][regC]);
    int zr = zt*16 + row;
    z[(pos0 + pc)*DIM_Z + zr] = pre + bz[zr];
  }
}

extern "C" void kernel_launch(void* const* d_in, const int* in_sizes, int n_in,
                              void* d_out, int out_size, void* d_ws, size_t ws_size,
                              hipStream_t stream){
  const float* h0    = (const float*)d_in[0];
  const float* s_seq = (const float*)d_in[1];
  const float* u_seq = (const float*)d_in[2];
  const float* W     = (const float*)d_in[3];
  const float* bias  = (const float*)d_in[4];
  const float* Bs    = (const float*)d_in[5];
  const float* Bu    = (const float*)d_in[6];
  const float* Wz    = (const float*)d_in[7];
  const float* bz    = (const float*)d_in[8];
  float* hseq = (float*)d_out;
  float* z    = hseq + (size_t)NBATCH*NT*DIM_H;
  unsigned* w = (unsigned*)d_ws;
  unsigned* wz32 = (unsigned*)((char*)d_ws + WZ_BYTE_OFF);

  k_init<<<4, 1024, 0, stream>>>(w);
  k_check<<<256, 256, 0, stream>>>(Bs, Bu, bias, w);
  k_wz<<<4, 256, 0, stream>>>(Wz, wz32);
  k_drive_general<<<2048, 256, 0, stream>>>(s_seq, u_seq, Bs, Bu, bias, hseq, w);
  {
    void* args[] = {(void*)&h0, (void*)&s_seq, (void*)&u_seq, (void*)&W,
                    (void*)&bias, (void*)&hseq, (void*)&w};
    hipError_t rc = hipLaunchCooperativeKernel((const void*)k_rnn, dim3(256), dim3(256),
                                               args, 0, stream);
    if (rc != hipSuccess){
      // 256 blocks == CU count, 1 block/CU by LDS budget: co-resident regardless.
      k_rnn<<<256, 256, 0, stream>>>(h0, s_seq, u_seq, W, bias, hseq, w);
    }
  }
  k_z<<<(NBATCH*NT)/16, 256, 0, stream>>>(hseq, wz32, bz, z);
}